// Round 5
// baseline (69.526 us; speedup 1.0000x reference)
//
#include <hip/hip_runtime.h>
#include <hip/hip_bf16.h>

// Problem constants:
//   X: (B=16, D=512, 60, 60) fp32 -> N = 3600
//   codewords: (K=32, D=512) fp32, scale: (K=32,) fp32
//   out E: (B, K, D) fp32
constexpr int BB = 16;
constexpr int DD = 512;
constexpr int NN = 3600;
constexpr int KK = 32;
constexpr int SB = 29;    // blocks per batch; each covers 128 n (2 subtiles of 64)
constexpr int STS = 2;    // subtiles per block

typedef __attribute__((ext_vector_type(8))) short short8;
typedef __attribute__((ext_vector_type(4))) float f32x4;

__device__ inline unsigned bf16pack(float a, float b) {
    unsigned ia = __float_as_uint(a), ib = __float_as_uint(b);
    ia = (ia + 0x7fffu + ((ia >> 16) & 1u)) >> 16;          // RNE to bf16
    ib = (ib + 0x7fffu + ((ib >> 16) & 1u)) & 0xffff0000u;
    return ia | ib;
}

// ---------------------------------------------------------------------------
// K0: Cbf[k][d] = bf16(Cw[k][d]);  sc2[k] = scale[k]*sum_d C[k,d]^2
// ---------------------------------------------------------------------------
__global__ __launch_bounds__(256) void k0_prep(const float* __restrict__ Cw,
                                               const float* __restrict__ scale,
                                               ushort* __restrict__ Cbf,
                                               float* __restrict__ sc2) {
    __shared__ float buf[8][32];
    const int t = threadIdx.x;
    const int k = t & 31;
    const int h = t >> 5;   // 0..7, 64 d's each
    const float4* row = reinterpret_cast<const float4*>(Cw + k * DD + h * 64);
    uint2* crow = reinterpret_cast<uint2*>(Cbf + k * DD + h * 64);
    float s = 0.f;
#pragma unroll
    for (int j = 0; j < 16; ++j) {
        float4 v = row[j];
        crow[j] = make_uint2(bf16pack(v.x, v.y), bf16pack(v.z, v.w));
        s += v.x * v.x + v.y * v.y + v.z * v.z + v.w * v.w;
    }
    buf[h][k] = s;
    __syncthreads();
    if (t < 32) {
        float tot = 0.f;
#pragma unroll
        for (int j = 0; j < 8; ++j) tot += buf[j][t];
        sc2[t] = scale[t] * tot;
    }
}

// ---------------------------------------------------------------------------
// KF: fused GEMM1 + softmax + GEMM2 partial accumulation.
// Grid: B*SB = 464 blocks x 256 threads (4 waves).
// Per subtile (64 n): phase A computes A[64n x 32k] into LDS (4 KB, bf16);
// phase B accumulates Ep'[d][k] with A-op = X[d][n] read straight from
// global (n-contiguous float4s, L1/L2-hot from phase A), B-op = As frags.
// Partial out: Ep[b][sb][k][d] fp32; asum_part[b][sb][k].
// ---------------------------------------------------------------------------
__global__ __launch_bounds__(256) void kf_fused(const float* __restrict__ X,
                                                const ushort* __restrict__ Cbf,
                                                const float* __restrict__ scale,
                                                const float* __restrict__ sc2,
                                                float* __restrict__ Ep,
                                                float* __restrict__ asum_part) {
    __shared__ ushort As[STS][KK][68];   // padded row: 136 B -> 2-bank rotation
    __shared__ float asw[4][KK];

    const int t = threadIdx.x;
    const int w = t >> 6;     // wave
    const int l = t & 63;
    const int q = l >> 4;     // 0..3
    const int r = l & 15;     // 0..15
    const int b = blockIdx.x / SB;
    const int sb = blockIdx.x % SB;
    const float* Xb = X + (size_t)b * DD * NN;
    const ushort* cb0 = Cbf + r * DD + q * 8;
    const ushort* cb1 = cb0 + 16 * DD;
    const float sk0 = scale[r], sk1 = scale[r + 16];
    const float sq0 = sc2[r],  sq1 = sc2[r + 16];

    f32x4 acc[8][2];
#pragma unroll
    for (int df = 0; df < 8; ++df) {
        acc[df][0] = (f32x4){0.f, 0.f, 0.f, 0.f};
        acc[df][1] = (f32x4){0.f, 0.f, 0.f, 0.f};
    }
    float as0t = 0.f, as1t = 0.f;

    for (int st = 0; st < STS; ++st) {
        const int n0 = sb * 128 + st * 64;

        // ================= phase A: GEMM1 + softmax =================
        const int nrow = n0 + w * 16 + r;
        const int nc = (nrow < NN) ? nrow : (NN - 1);
        const float* Xp = Xb + (size_t)(q * 8) * NN + nc;

        f32x4 a0 = {0.f, 0.f, 0.f, 0.f};
        f32x4 a1 = {0.f, 0.f, 0.f, 0.f};
        float x2p = 0.f;

        for (int s = 0; s < 16; s += 2) {
            float xv[16];
#pragma unroll
            for (int u = 0; u < 2; ++u)
#pragma unroll
                for (int j = 0; j < 8; ++j)
                    xv[u * 8 + j] = Xp[(size_t)((s + u) * 32 + j) * NN];
#pragma unroll
            for (int u = 0; u < 2; ++u) {
#pragma unroll
                for (int j = 0; j < 8; ++j)
                    x2p = fmaf(xv[u * 8 + j], xv[u * 8 + j], x2p);
                union { short8 s8; unsigned uu[4]; } a;
                a.uu[0] = bf16pack(xv[u * 8 + 0], xv[u * 8 + 1]);
                a.uu[1] = bf16pack(xv[u * 8 + 2], xv[u * 8 + 3]);
                a.uu[2] = bf16pack(xv[u * 8 + 4], xv[u * 8 + 5]);
                a.uu[3] = bf16pack(xv[u * 8 + 6], xv[u * 8 + 7]);
                const short8 c0 = *reinterpret_cast<const short8*>(cb0 + (s + u) * 32);
                const short8 c1 = *reinterpret_cast<const short8*>(cb1 + (s + u) * 32);
                a0 = __builtin_amdgcn_mfma_f32_16x16x32_bf16(a.s8, c0, a0, 0, 0, 0);
                a1 = __builtin_amdgcn_mfma_f32_16x16x32_bf16(a.s8, c1, a1, 0, 0, 0);
            }
        }

        float x2f = x2p;
        x2f += __shfl_xor(x2f, 16);
        x2f += __shfl_xor(x2f, 32);

        float e0v[4], e1v[4];
        float as0 = 0.f, as1 = 0.f;
#pragma unroll
        for (int i = 0; i < 4; ++i) {
            const float x2v = __shfl(x2f, 4 * q + i);
            float sl0 = fmaf(sk0, x2v, sq0) - 2.f * sk0 * a0[i];
            float sl1 = fmaf(sk1, x2v, sq1) - 2.f * sk1 * a1[i];
            float m = fmaxf(sl0, sl1);
            m = fmaxf(m, __shfl_xor(m, 1));
            m = fmaxf(m, __shfl_xor(m, 2));
            m = fmaxf(m, __shfl_xor(m, 4));
            m = fmaxf(m, __shfl_xor(m, 8));
            float e0 = __expf(sl0 - m), e1 = __expf(sl1 - m);
            float ssum = e0 + e1;
            ssum += __shfl_xor(ssum, 1);
            ssum += __shfl_xor(ssum, 2);
            ssum += __shfl_xor(ssum, 4);
            ssum += __shfl_xor(ssum, 8);
            const float inv = 1.f / ssum;
            e0 *= inv; e1 *= inv;
            if (n0 + w * 16 + 4 * q + i >= NN) { e0 = 0.f; e1 = 0.f; }
            e0v[i] = e0; e1v[i] = e1;
            as0 += e0; as1 += e1;
        }
        as0t += as0; as1t += as1;

        *reinterpret_cast<uint2*>(&As[st][r][w * 16 + 4 * q]) =
            make_uint2(bf16pack(e0v[0], e0v[1]), bf16pack(e0v[2], e0v[3]));
        *reinterpret_cast<uint2*>(&As[st][r + 16][w * 16 + 4 * q]) =
            make_uint2(bf16pack(e1v[0], e1v[1]), bf16pack(e1v[2], e1v[3]));
        __syncthreads();

        // ================= phase B: GEMM2 accumulate =================
        // B-frags (col k, kdim n): reused across all 8 d-frags
        const short8 bf00 = *reinterpret_cast<const short8*>(&As[st][r][q * 8]);
        const short8 bf01 = *reinterpret_cast<const short8*>(&As[st][r + 16][q * 8]);
        const short8 bf10 = *reinterpret_cast<const short8*>(&As[st][r][32 + q * 8]);
        const short8 bf11 = *reinterpret_cast<const short8*>(&As[st][r + 16][32 + q * 8]);

#pragma unroll
        for (int df = 0; df < 8; ++df) {
            const int d = w * 128 + df * 16 + r;   // A-frag row
            const float* xr = Xb + (size_t)d * NN;
#pragma unroll
            for (int step = 0; step < 2; ++step) {
                int off = n0 + step * 32 + q * 8;
                if (off > NN - 8) off = NN - 8;    // OOB groups have As==0
                const float4 f0 = *reinterpret_cast<const float4*>(xr + off);
                const float4 f1 = *reinterpret_cast<const float4*>(xr + off + 4);
                union { short8 s8; unsigned uu[4]; } xa;
                xa.uu[0] = bf16pack(f0.x, f0.y);
                xa.uu[1] = bf16pack(f0.z, f0.w);
                xa.uu[2] = bf16pack(f1.x, f1.y);
                xa.uu[3] = bf16pack(f1.z, f1.w);
                acc[df][0] = __builtin_amdgcn_mfma_f32_16x16x32_bf16(
                    xa.s8, step ? bf10 : bf00, acc[df][0], 0, 0, 0);
                acc[df][1] = __builtin_amdgcn_mfma_f32_16x16x32_bf16(
                    xa.s8, step ? bf11 : bf01, acc[df][1], 0, 0, 0);
            }
        }
        // no barrier needed: next subtile uses the other As buffer
    }

    // ---- asum partial for this block (sum over its 128 n) ----
    as0t += __shfl_xor(as0t, 16); as0t += __shfl_xor(as0t, 32);
    as1t += __shfl_xor(as1t, 16); as1t += __shfl_xor(as1t, 32);
    if (l < 16) { asw[w][r] = as0t; asw[w][r + 16] = as1t; }
    __syncthreads();
    if (t < KK)
        asum_part[((size_t)b * SB + sb) * KK + t] =
            asw[0][t] + asw[1][t] + asw[2][t] + asw[3][t];

    // ---- store Ep partial: D-frag row = d (q*4+i contiguous) -> float4 ----
    float* ep = Ep + (size_t)(b * SB + sb) * KK * DD;
#pragma unroll
    for (int df = 0; df < 8; ++df) {
#pragma unroll
        for (int kf = 0; kf < 2; ++kf) {
            const int k = kf * 16 + r;
            const int d = w * 128 + df * 16 + q * 4;
            *reinterpret_cast<f32x4*>(ep + (size_t)k * DD + d) = acc[df][kf];
        }
    }
}

// ---------------------------------------------------------------------------
// K3: E[b,k,d] = sum_sb Ep[b,sb,k,d] - Asum[b,k]*C[k,d]
// Grid: B*K = 512 blocks x 256 threads (2 d's per thread).
// ---------------------------------------------------------------------------
__global__ __launch_bounds__(256) void k3_final(const float* __restrict__ Ep,
                                                const float* __restrict__ asum_part,
                                                const float* __restrict__ Cw,
                                                float* __restrict__ E) {
    const int t = threadIdx.x;
    const int b = blockIdx.x >> 5, k = blockIdx.x & 31;

    float asum = 0.f;
#pragma unroll
    for (int sb = 0; sb < SB; ++sb)   // uniform addresses -> scalar loads
        asum += asum_part[((size_t)b * SB + sb) * KK + k];

#pragma unroll
    for (int h = 0; h < 2; ++h) {
        const int d = t + h * 256;
        float s2 = 0.f;
#pragma unroll 4
        for (int sb = 0; sb < SB; ++sb)
            s2 += Ep[(((size_t)b * SB + sb) * KK + k) * DD + d];
        E[((size_t)b * KK + k) * DD + d] = s2 - asum * Cw[k * DD + d];
    }
}

// ---------------------------------------------------------------------------
extern "C" void kernel_launch(void* const* d_in, const int* in_sizes, int n_in,
                              void* d_out, int out_size, void* d_ws, size_t ws_size,
                              hipStream_t stream) {
    const float* X     = (const float*)d_in[0];
    const float* Cw    = (const float*)d_in[1];
    const float* scale = (const float*)d_in[2];
    float* E = (float*)d_out;

    // ws layout (float slots):
    //   Ep        : 16*29*32*512 = 7,602,176
    //   asum_part : 464*32       = 14,848
    //   sc2       : 32
    //   Cbf       : 32*512 ushort = 8192 float slots        (~30.5 MB total)
    float* ws = (float*)d_ws;
    float* Ep = ws;
    float* asum_part = Ep + (size_t)BB * SB * KK * DD;
    float* sc2 = asum_part + (size_t)BB * SB * KK;
    ushort* Cbf = (ushort*)(sc2 + KK);

    k0_prep<<<dim3(1), dim3(256), 0, stream>>>(Cw, scale, Cbf, sc2);
    kf_fused<<<dim3(BB * SB), dim3(256), 0, stream>>>(X, Cbf, scale, sc2, Ep, asum_part);
    k3_final<<<dim3(BB * KK), dim3(256), 0, stream>>>(Ep, asum_part, Cw, E);
}

// Round 6
// 68.300 us; speedup vs baseline: 1.0180x; 1.0180x over previous
//
#include <hip/hip_runtime.h>
#include <hip/hip_bf16.h>

// Problem constants:
//   X: (B=16, D=512, 60, 60) fp32 -> N = 3600
//   codewords: (K=32, D=512) fp32, scale: (K=32,) fp32
//   out E: (B, K, D) fp32
constexpr int BB = 16;
constexpr int DD = 512;
constexpr int NN = 3600;
constexpr int KK = 32;
constexpr int SB = 29;    // blocks per batch; each covers 128 n

typedef __attribute__((ext_vector_type(8))) short short8;
typedef __attribute__((ext_vector_type(4))) float f32x4;

__device__ inline unsigned bf16pack(float a, float b) {
    unsigned ia = __float_as_uint(a), ib = __float_as_uint(b);
    ia = (ia + 0x7fffu + ((ia >> 16) & 1u)) >> 16;          // RNE to bf16
    ib = (ib + 0x7fffu + ((ib >> 16) & 1u)) & 0xffff0000u;
    return ia | ib;
}

// ---------------------------------------------------------------------------
// K0: Cbf[k][d] = bf16(Cw[k][d]);  sc2[k] = scale[k]*sum_d C[k,d]^2
// ---------------------------------------------------------------------------
__global__ __launch_bounds__(256) void k0_prep(const float* __restrict__ Cw,
                                               const float* __restrict__ scale,
                                               ushort* __restrict__ Cbf,
                                               float* __restrict__ sc2) {
    __shared__ float buf[8][32];
    const int t = threadIdx.x;
    const int k = t & 31;
    const int h = t >> 5;   // 0..7, 64 d's each
    const float4* row = reinterpret_cast<const float4*>(Cw + k * DD + h * 64);
    uint2* crow = reinterpret_cast<uint2*>(Cbf + k * DD + h * 64);
    float s = 0.f;
#pragma unroll
    for (int j = 0; j < 16; ++j) {
        float4 v = row[j];
        crow[j] = make_uint2(bf16pack(v.x, v.y), bf16pack(v.z, v.w));
        s += v.x * v.x + v.y * v.y + v.z * v.z + v.w * v.w;
    }
    buf[h][k] = s;
    __syncthreads();
    if (t < 32) {
        float tot = 0.f;
#pragma unroll
        for (int j = 0; j < 8; ++j) tot += buf[j][t];
        sc2[t] = scale[t] * tot;
    }
}

// ---------------------------------------------------------------------------
// KF: fused GEMM1 + softmax + GEMM2 partial accumulation.
// Grid: B*SB = 464 blocks x 512 threads (8 waves).
// Phase A: 8 waves x 16 n = 128 n in one pass -> A[128n x 32k] in LDS (bf16).
// Phase B: wave w owns d in [w*64, w*64+64); A-op = X[d][n] float4 from
// global (L1/L2-hot from phase A), B-op = As frags; 4 n-steps of 32.
// Partial out: Ep[b][sb][k][d] fp32; asum_part[b][sb][k].
// ---------------------------------------------------------------------------
__global__ __launch_bounds__(512) void kf_fused(const float* __restrict__ X,
                                                const ushort* __restrict__ Cbf,
                                                const float* __restrict__ scale,
                                                const float* __restrict__ sc2,
                                                float* __restrict__ Ep,
                                                float* __restrict__ asum_part) {
    __shared__ ushort As[2][KK][68];   // two 64-n subtiles; 136 B rows
    __shared__ float asw[8][KK];

    const int t = threadIdx.x;
    const int w = t >> 6;     // wave 0..7
    const int l = t & 63;
    const int q = l >> 4;     // 0..3
    const int r = l & 15;     // 0..15
    const int b = blockIdx.x / SB;
    const int sb = blockIdx.x % SB;
    const int n0 = sb * 128;
    const float* Xb = X + (size_t)b * DD * NN;
    const ushort* cb0 = Cbf + r * DD + q * 8;
    const ushort* cb1 = cb0 + 16 * DD;
    const float sk0 = scale[r], sk1 = scale[r + 16];
    const float sq0 = sc2[r],  sq1 = sc2[r + 16];

    // ================= phase A: GEMM1 + softmax (wave owns 16 n) ==========
    const int nrow = n0 + w * 16 + r;
    const int nc = (nrow < NN) ? nrow : (NN - 1);
    const float* Xp = Xb + (size_t)(q * 8) * NN + nc;

    f32x4 a0 = {0.f, 0.f, 0.f, 0.f};
    f32x4 a1 = {0.f, 0.f, 0.f, 0.f};
    float x2p = 0.f;

#pragma unroll 4
    for (int s = 0; s < 16; ++s) {
        float xv[8];
#pragma unroll
        for (int j = 0; j < 8; ++j) xv[j] = Xp[(size_t)(s * 32 + j) * NN];
#pragma unroll
        for (int j = 0; j < 8; ++j) x2p = fmaf(xv[j], xv[j], x2p);
        union { short8 s8; unsigned uu[4]; } a;
        a.uu[0] = bf16pack(xv[0], xv[1]);
        a.uu[1] = bf16pack(xv[2], xv[3]);
        a.uu[2] = bf16pack(xv[4], xv[5]);
        a.uu[3] = bf16pack(xv[6], xv[7]);
        const short8 c0 = *reinterpret_cast<const short8*>(cb0 + s * 32);
        const short8 c1 = *reinterpret_cast<const short8*>(cb1 + s * 32);
        a0 = __builtin_amdgcn_mfma_f32_16x16x32_bf16(a.s8, c0, a0, 0, 0, 0);
        a1 = __builtin_amdgcn_mfma_f32_16x16x32_bf16(a.s8, c1, a1, 0, 0, 0);
    }

    float x2f = x2p;
    x2f += __shfl_xor(x2f, 16);
    x2f += __shfl_xor(x2f, 32);

    float e0v[4], e1v[4];
    float as0 = 0.f, as1 = 0.f;
#pragma unroll
    for (int i = 0; i < 4; ++i) {
        const float x2v = __shfl(x2f, 4 * q + i);
        float sl0 = fmaf(sk0, x2v, sq0) - 2.f * sk0 * a0[i];
        float sl1 = fmaf(sk1, x2v, sq1) - 2.f * sk1 * a1[i];
        float m = fmaxf(sl0, sl1);
        m = fmaxf(m, __shfl_xor(m, 1));
        m = fmaxf(m, __shfl_xor(m, 2));
        m = fmaxf(m, __shfl_xor(m, 4));
        m = fmaxf(m, __shfl_xor(m, 8));
        float e0 = __expf(sl0 - m), e1 = __expf(sl1 - m);
        float ssum = e0 + e1;
        ssum += __shfl_xor(ssum, 1);
        ssum += __shfl_xor(ssum, 2);
        ssum += __shfl_xor(ssum, 4);
        ssum += __shfl_xor(ssum, 8);
        const float inv = 1.f / ssum;
        e0 *= inv; e1 *= inv;
        if (n0 + w * 16 + 4 * q + i >= NN) { e0 = 0.f; e1 = 0.f; }
        e0v[i] = e0; e1v[i] = e1;
        as0 += e0; as1 += e1;
    }

    // As[subtile][k][n_local]: subtile = w>>2, n_local = (w&3)*16 + 4q+i
    *reinterpret_cast<uint2*>(&As[w >> 2][r][(w & 3) * 16 + 4 * q]) =
        make_uint2(bf16pack(e0v[0], e0v[1]), bf16pack(e0v[2], e0v[3]));
    *reinterpret_cast<uint2*>(&As[w >> 2][r + 16][(w & 3) * 16 + 4 * q]) =
        make_uint2(bf16pack(e1v[0], e1v[1]), bf16pack(e1v[2], e1v[3]));

    // asum partial: lane sums its 4 n's; reduce over q
    as0 += __shfl_xor(as0, 16); as0 += __shfl_xor(as0, 32);
    as1 += __shfl_xor(as1, 16); as1 += __shfl_xor(as1, 32);
    if (l < 16) { asw[w][r] = as0; asw[w][r + 16] = as1; }
    __syncthreads();

    if (t < KK) {
        float s = 0.f;
#pragma unroll
        for (int j = 0; j < 8; ++j) s += asw[j][t];
        asum_part[((size_t)b * SB + sb) * KK + t] = s;
    }

    // ================= phase B: GEMM2 accumulate ==========================
    // B-frags for the 4 n-steps (step>>1 = subtile, step&1 = 32-half)
    short8 bfr0[4], bfr1[4];
#pragma unroll
    for (int step = 0; step < 4; ++step) {
        bfr0[step] = *reinterpret_cast<const short8*>(
            &As[step >> 1][r][(step & 1) * 32 + q * 8]);
        bfr1[step] = *reinterpret_cast<const short8*>(
            &As[step >> 1][r + 16][(step & 1) * 32 + q * 8]);
    }

    f32x4 acc[4][2];
#pragma unroll
    for (int df = 0; df < 4; ++df) {
        acc[df][0] = (f32x4){0.f, 0.f, 0.f, 0.f};
        acc[df][1] = (f32x4){0.f, 0.f, 0.f, 0.f};
    }

#pragma unroll
    for (int df = 0; df < 4; ++df) {
        const int d = w * 64 + df * 16 + r;   // A-frag row
        const float* xr = Xb + (size_t)d * NN;
#pragma unroll
        for (int step = 0; step < 4; ++step) {
            int off = n0 + step * 32 + q * 8;
            if (off > NN - 8) off = NN - 8;   // OOB groups have As==0 (8|3600)
            const float4 f0 = *reinterpret_cast<const float4*>(xr + off);
            const float4 f1 = *reinterpret_cast<const float4*>(xr + off + 4);
            union { short8 s8; unsigned uu[4]; } xa;
            xa.uu[0] = bf16pack(f0.x, f0.y);
            xa.uu[1] = bf16pack(f0.z, f0.w);
            xa.uu[2] = bf16pack(f1.x, f1.y);
            xa.uu[3] = bf16pack(f1.z, f1.w);
            acc[df][0] = __builtin_amdgcn_mfma_f32_16x16x32_bf16(
                xa.s8, bfr0[step], acc[df][0], 0, 0, 0);
            acc[df][1] = __builtin_amdgcn_mfma_f32_16x16x32_bf16(
                xa.s8, bfr1[step], acc[df][1], 0, 0, 0);
        }
    }

    // ---- store Ep partial: D-frag row = d (q*4+i contiguous) -> float4 ----
    float* ep = Ep + (size_t)(b * SB + sb) * KK * DD;
#pragma unroll
    for (int df = 0; df < 4; ++df) {
#pragma unroll
        for (int kf = 0; kf < 2; ++kf) {
            const int k = kf * 16 + r;
            const int d = w * 64 + df * 16 + q * 4;
            *reinterpret_cast<f32x4*>(ep + (size_t)k * DD + d) = acc[df][kf];
        }
    }
}

// ---------------------------------------------------------------------------
// K3: E[b,k,d] = sum_sb Ep[b,sb,k,d] - Asum[b,k]*C[k,d]
// Grid: B*K = 512 blocks x 256 threads (2 d's per thread).
// ---------------------------------------------------------------------------
__global__ __launch_bounds__(256) void k3_final(const float* __restrict__ Ep,
                                                const float* __restrict__ asum_part,
                                                const float* __restrict__ Cw,
                                                float* __restrict__ E) {
    const int t = threadIdx.x;
    const int b = blockIdx.x >> 5, k = blockIdx.x & 31;

    float asum = 0.f;
#pragma unroll
    for (int sb = 0; sb < SB; ++sb)   // uniform addresses -> scalar loads
        asum += asum_part[((size_t)b * SB + sb) * KK + k];

#pragma unroll
    for (int h = 0; h < 2; ++h) {
        const int d = t + h * 256;
        float s2 = 0.f;
#pragma unroll 4
        for (int sb = 0; sb < SB; ++sb)
            s2 += Ep[(((size_t)b * SB + sb) * KK + k) * DD + d];
        E[((size_t)b * KK + k) * DD + d] = s2 - asum * Cw[k * DD + d];
    }
}

// ---------------------------------------------------------------------------
extern "C" void kernel_launch(void* const* d_in, const int* in_sizes, int n_in,
                              void* d_out, int out_size, void* d_ws, size_t ws_size,
                              hipStream_t stream) {
    const float* X     = (const float*)d_in[0];
    const float* Cw    = (const float*)d_in[1];
    const float* scale = (const float*)d_in[2];
    float* E = (float*)d_out;

    // ws layout (float slots):
    //   Ep        : 16*29*32*512 = 7,602,176
    //   asum_part : 464*32       = 14,848
    //   sc2       : 32
    //   Cbf       : 32*512 ushort = 8192 float slots        (~30.5 MB total)
    float* ws = (float*)d_ws;
    float* Ep = ws;
    float* asum_part = Ep + (size_t)BB * SB * KK * DD;
    float* sc2 = asum_part + (size_t)BB * SB * KK;
    ushort* Cbf = (ushort*)(sc2 + KK);

    k0_prep<<<dim3(1), dim3(256), 0, stream>>>(Cw, scale, Cbf, sc2);
    kf_fused<<<dim3(BB * SB), dim3(512), 0, stream>>>(X, Cbf, scale, sc2, Ep, asum_part);
    k3_final<<<dim3(BB * KK), dim3(256), 0, stream>>>(Ep, asum_part, Cw, E);
}

// Round 7
// 59.512 us; speedup vs baseline: 1.1683x; 1.1477x over previous
//
#include <hip/hip_runtime.h>
#include <hip/hip_bf16.h>

// Problem constants:
//   X: (B=16, D=512, 60, 60) fp32 -> N = 3600
//   codewords: (K=32, D=512) fp32, scale: (K=32,) fp32
//   out E: (B, K, D) fp32
constexpr int BB = 16;
constexpr int DD = 512;
constexpr int NN = 3600;
constexpr int KK = 32;
constexpr int SB = 29;     // n-windows of 128 per batch (28 full + 1 of 16)
constexpr int WIN = 128;

typedef __attribute__((ext_vector_type(8))) short short8;
typedef __attribute__((ext_vector_type(4))) float f32x4;

__device__ inline unsigned bf16pack(float a, float b) {
    unsigned ia = __float_as_uint(a), ib = __float_as_uint(b);
    ia = (ia + 0x7fffu + ((ia >> 16) & 1u)) >> 16;          // RNE to bf16
    ib = (ib + 0x7fffu + ((ib >> 16) & 1u)) & 0xffff0000u;
    return ia | ib;
}

// ---------------------------------------------------------------------------
// K0: Cbf[k][d] = bf16(Cw[k][d]);  sc2[k] = scale[k]*sum_d C[k,d]^2
// ---------------------------------------------------------------------------
__global__ __launch_bounds__(256) void k0_prep(const float* __restrict__ Cw,
                                               const float* __restrict__ scale,
                                               ushort* __restrict__ Cbf,
                                               float* __restrict__ sc2) {
    __shared__ float buf[8][32];
    const int t = threadIdx.x;
    const int k = t & 31;
    const int h = t >> 5;   // 0..7, 64 d's each
    const float4* row = reinterpret_cast<const float4*>(Cw + k * DD + h * 64);
    uint2* crow = reinterpret_cast<uint2*>(Cbf + k * DD + h * 64);
    float s = 0.f;
#pragma unroll
    for (int j = 0; j < 16; ++j) {
        float4 v = row[j];
        crow[j] = make_uint2(bf16pack(v.x, v.y), bf16pack(v.z, v.w));
        s += v.x * v.x + v.y * v.y + v.z * v.z + v.w * v.w;
    }
    buf[h][k] = s;
    __syncthreads();
    if (t < 32) {
        float tot = 0.f;
#pragma unroll
        for (int j = 0; j < 8; ++j) tot += buf[j][t];
        sc2[t] = scale[t] * tot;
    }
}

// ---------------------------------------------------------------------------
// KF: fused. One block per (b, 128-n window). 512 threads (8 waves).
// Stage: X[:, window] fp32 read ONCE, fully coalesced, -> bf16 LDS tile
//   tile[d][n] with elem index d*128 + (n ^ ((d&7)<<3))  (T2 XOR swizzle),
//   chunk-pipelined (64 d per chunk) with phase-A MFMA on the prev chunk.
//   x2 (fp32, exact) accumulated during staging, LDS-reduced.
// Phase A: GEMM1 xc = X^T C^T; A-frags = 8x ds_read_u16 column reads.
// Softmax -> As2[k][n] (bf16, swizzled) + asum partials.
// Phase B: GEMM2 from the SAME tile, row reads ds_read_b128 (swizzled).
// Out: Ep[b][sb][k][d] fp32 partials; k3 reduces.
// ---------------------------------------------------------------------------
__global__ __launch_bounds__(512) void kf_fused(const float* __restrict__ X,
                                                const ushort* __restrict__ Cbf,
                                                const float* __restrict__ scale,
                                                const float* __restrict__ sc2,
                                                float* __restrict__ Ep,
                                                float* __restrict__ asum_part) {
    __shared__ ushort tile[DD * WIN];     // 128 KB
    __shared__ ushort As2[KK * WIN];      // 8 KB
    __shared__ float x2part[16][WIN];     // 8 KB
    __shared__ float x2s[WIN];
    __shared__ float asw[8][KK];

    const int t = threadIdx.x;
    const int w = t >> 6;     // wave 0..7
    const int l = t & 63;
    const int q = l >> 4;     // 0..3
    const int r = l & 15;     // 0..15
    const int b = blockIdx.x / SB;
    const int sb = blockIdx.x % SB;
    const int n0 = sb * WIN;

    // staging assignment: thread (ng, dgs) loads 4 n x 4 d per chunk
    const int ng = t & 31;    // n-group of 4
    const int dgs = t >> 5;   // 0..15
    int nst = n0 + ng * 4;
    if (nst > NN - 4) nst = NN - 4;
    const float* xsrc = X + (size_t)b * DD * NN + nst;

    const ushort* cb0 = Cbf + r * DD + q * 8;
    const ushort* cb1 = cb0 + 16 * DD;
    const int nloc = w * 16 + r;   // phase-A A-frag row (n)

    float x2loc[4] = {0.f, 0.f, 0.f, 0.f};
    f32x4 a0 = {0.f, 0.f, 0.f, 0.f};
    f32x4 a1 = {0.f, 0.f, 0.f, 0.f};

    float4 cur[4];
#pragma unroll
    for (int i = 0; i < 4; ++i)
        cur[i] = *reinterpret_cast<const float4*>(xsrc + (size_t)(dgs * 4 + i) * NN);

#pragma unroll
    for (int j = 0; j < 8; ++j) {
        float4 nxt[4];
        if (j < 7) {
#pragma unroll
            for (int i = 0; i < 4; ++i)
                nxt[i] = *reinterpret_cast<const float4*>(
                    xsrc + (size_t)((j + 1) * 64 + dgs * 4 + i) * NN);
        }
        // write chunk j (x2 + pack + swizzled LDS write)
#pragma unroll
        for (int i = 0; i < 4; ++i) {
            const float4 v = cur[i];
            x2loc[0] = fmaf(v.x, v.x, x2loc[0]);
            x2loc[1] = fmaf(v.y, v.y, x2loc[1]);
            x2loc[2] = fmaf(v.z, v.z, x2loc[2]);
            x2loc[3] = fmaf(v.w, v.w, x2loc[3]);
            const int d = j * 64 + dgs * 4 + i;
            *reinterpret_cast<uint2*>(&tile[d * 128 + ((ng * 4) ^ ((d & 7) << 3))]) =
                make_uint2(bf16pack(v.x, v.y), bf16pack(v.z, v.w));
        }
        __syncthreads();
        // phase A on chunk j: steps 2j, 2j+1 (32 d each)
#pragma unroll
        for (int u = 0; u < 2; ++u) {
            const int s = 2 * j + u;
            union { short8 s8; ushort us[8]; } af;
#pragma unroll
            for (int jj = 0; jj < 8; ++jj) {
                const int d = s * 32 + q * 8 + jj;   // d&7 == jj
                af.us[jj] = tile[d * 128 + (nloc ^ (jj << 3))];
            }
            const short8 c0 = *reinterpret_cast<const short8*>(cb0 + s * 32);
            const short8 c1 = *reinterpret_cast<const short8*>(cb1 + s * 32);
            a0 = __builtin_amdgcn_mfma_f32_16x16x32_bf16(af.s8, c0, a0, 0, 0, 0);
            a1 = __builtin_amdgcn_mfma_f32_16x16x32_bf16(af.s8, c1, a1, 0, 0, 0);
        }
        if (j < 7) {
#pragma unroll
            for (int i = 0; i < 4; ++i) cur[i] = nxt[i];
        }
    }

    // ---- x2 reduction ----
    *reinterpret_cast<f32x4*>(&x2part[dgs][ng * 4]) =
        (f32x4){x2loc[0], x2loc[1], x2loc[2], x2loc[3]};
    __syncthreads();
    if (t < WIN) {
        float s = 0.f;
#pragma unroll
        for (int dg = 0; dg < 16; ++dg) s += x2part[dg][t];
        x2s[t] = s;
    }
    __syncthreads();

    // ---- softmax (lane (q,r): n = w*16 + 4q + i, k = r / r+16) ----
    const float sk0 = scale[r], sk1 = scale[r + 16];
    const float sq0 = sc2[r],  sq1 = sc2[r + 16];
    float e0v[4], e1v[4];
    float as0 = 0.f, as1 = 0.f;
#pragma unroll
    for (int i = 0; i < 4; ++i) {
        const float x2v = x2s[w * 16 + 4 * q + i];
        float sl0 = fmaf(sk0, x2v, sq0) - 2.f * sk0 * a0[i];
        float sl1 = fmaf(sk1, x2v, sq1) - 2.f * sk1 * a1[i];
        float m = fmaxf(sl0, sl1);
        m = fmaxf(m, __shfl_xor(m, 1));
        m = fmaxf(m, __shfl_xor(m, 2));
        m = fmaxf(m, __shfl_xor(m, 4));
        m = fmaxf(m, __shfl_xor(m, 8));
        float e0 = __expf(sl0 - m), e1 = __expf(sl1 - m);
        float ssum = e0 + e1;
        ssum += __shfl_xor(ssum, 1);
        ssum += __shfl_xor(ssum, 2);
        ssum += __shfl_xor(ssum, 4);
        ssum += __shfl_xor(ssum, 8);
        const float inv = 1.f / ssum;
        e0 *= inv; e1 *= inv;
        if (n0 + w * 16 + 4 * q + i >= NN) { e0 = 0.f; e1 = 0.f; }
        e0v[i] = e0; e1v[i] = e1;
        as0 += e0; as1 += e1;
    }
    // As2 writes (swizzle key (k&7) == (r&7) for both rows r and r+16)
    *reinterpret_cast<uint2*>(&As2[r * 128 + ((w * 16 + 4 * q) ^ ((r & 7) << 3))]) =
        make_uint2(bf16pack(e0v[0], e0v[1]), bf16pack(e0v[2], e0v[3]));
    *reinterpret_cast<uint2*>(&As2[(r + 16) * 128 + ((w * 16 + 4 * q) ^ ((r & 7) << 3))]) =
        make_uint2(bf16pack(e1v[0], e1v[1]), bf16pack(e1v[2], e1v[3]));

    as0 += __shfl_xor(as0, 16); as0 += __shfl_xor(as0, 32);
    as1 += __shfl_xor(as1, 16); as1 += __shfl_xor(as1, 32);
    if (l < 16) { asw[w][r] = as0; asw[w][r + 16] = as1; }
    __syncthreads();
    if (t < KK) {
        float s = 0.f;
#pragma unroll
        for (int jw = 0; jw < 8; ++jw) s += asw[jw][t];
        asum_part[((size_t)b * SB + sb) * KK + t] = s;
    }

    // ---- phase B: GEMM2 from the tile; wave w owns d in [w*64, w*64+64) ----
    short8 bfr0[4], bfr1[4];
#pragma unroll
    for (int step = 0; step < 4; ++step) {
        bfr0[step] = *reinterpret_cast<const short8*>(
            &As2[r * 128 + ((step * 32 + q * 8) ^ ((r & 7) << 3))]);
        bfr1[step] = *reinterpret_cast<const short8*>(
            &As2[(r + 16) * 128 + ((step * 32 + q * 8) ^ ((r & 7) << 3))]);
    }

    f32x4 acc[4][2];
#pragma unroll
    for (int df = 0; df < 4; ++df) {
        acc[df][0] = (f32x4){0.f, 0.f, 0.f, 0.f};
        acc[df][1] = (f32x4){0.f, 0.f, 0.f, 0.f};
    }

#pragma unroll
    for (int df = 0; df < 4; ++df) {
        const int d = w * 64 + df * 16 + r;   // A-frag row; d&7 == r&7
#pragma unroll
        for (int step = 0; step < 4; ++step) {
            const short8 xa = *reinterpret_cast<const short8*>(
                &tile[d * 128 + ((step * 32 + q * 8) ^ ((r & 7) << 3))]);
            acc[df][0] = __builtin_amdgcn_mfma_f32_16x16x32_bf16(
                xa, bfr0[step], acc[df][0], 0, 0, 0);
            acc[df][1] = __builtin_amdgcn_mfma_f32_16x16x32_bf16(
                xa, bfr1[step], acc[df][1], 0, 0, 0);
        }
    }

    // store Ep partial: D-frag row = d = w*64 + df*16 + 4q+i, col k = r(+16)
    float* ep = Ep + (size_t)(b * SB + sb) * KK * DD;
#pragma unroll
    for (int df = 0; df < 4; ++df) {
#pragma unroll
        for (int kf = 0; kf < 2; ++kf) {
            const int k = kf * 16 + r;
            const int d = w * 64 + df * 16 + q * 4;
            *reinterpret_cast<f32x4*>(ep + (size_t)k * DD + d) = acc[df][kf];
        }
    }
}

// ---------------------------------------------------------------------------
// K3: E[b,k,d] = sum_sb Ep[b,sb,k,d] - Asum[b,k]*C[k,d]
// Grid: B*K = 512 blocks x 256 threads (2 d's per thread).
// ---------------------------------------------------------------------------
__global__ __launch_bounds__(256) void k3_final(const float* __restrict__ Ep,
                                                const float* __restrict__ asum_part,
                                                const float* __restrict__ Cw,
                                                float* __restrict__ E) {
    const int t = threadIdx.x;
    const int b = blockIdx.x >> 5, k = blockIdx.x & 31;

    float asum = 0.f;
#pragma unroll
    for (int sb = 0; sb < SB; ++sb)
        asum += asum_part[((size_t)b * SB + sb) * KK + k];

#pragma unroll
    for (int h = 0; h < 2; ++h) {
        const int d = t + h * 256;
        float s2 = 0.f;
#pragma unroll 4
        for (int sb = 0; sb < SB; ++sb)
            s2 += Ep[(((size_t)b * SB + sb) * KK + k) * DD + d];
        E[((size_t)b * KK + k) * DD + d] = s2 - asum * Cw[k * DD + d];
    }
}

// ---------------------------------------------------------------------------
extern "C" void kernel_launch(void* const* d_in, const int* in_sizes, int n_in,
                              void* d_out, int out_size, void* d_ws, size_t ws_size,
                              hipStream_t stream) {
    const float* X     = (const float*)d_in[0];
    const float* Cw    = (const float*)d_in[1];
    const float* scale = (const float*)d_in[2];
    float* E = (float*)d_out;

    // ws layout (float slots):
    //   Ep        : 16*29*32*512 = 7,602,176
    //   asum_part : 464*32       = 14,848
    //   sc2       : 32
    //   Cbf       : 32*512 ushort = 8192 float slots        (~30.5 MB total)
    float* ws = (float*)d_ws;
    float* Ep = ws;
    float* asum_part = Ep + (size_t)BB * SB * KK * DD;
    float* sc2 = asum_part + (size_t)BB * SB * KK;
    ushort* Cbf = (ushort*)(sc2 + KK);

    k0_prep<<<dim3(1), dim3(256), 0, stream>>>(Cw, scale, Cbf, sc2);
    kf_fused<<<dim3(BB * SB), dim3(512), 0, stream>>>(X, Cbf, scale, sc2, Ep, asum_part);
    k3_final<<<dim3(BB * KK), dim3(256), 0, stream>>>(Ep, asum_part, Cw, E);
}